// Round 6
// baseline (534.721 us; speedup 1.0000x reference)
//
#include <hip/hip_runtime.h>
#include <math.h>

// NNFM loss on MI355X.
// loss = mean_i (1 - max_j (xhat_i . shat_j)),  xhat/shat = column-normalized feats.
// R2: XOR-swizzled LDS -> bank conflicts 1.5e8 -> 0 (475us).
// R3: 256^2 tile, 8 waves, 4-phase schedule + counted vmcnt + setprio (465us).
// R4: double-set read-ahead -> VGPR spill (WRITE_SIZE 79MB), reverted.
// R5: fp8 e4m3 operands, BK=128 -> 320us GEMM, MfmaUtil 55% (fp8==bf16 rate wall).
// R6: MX-scaled MFMA 16x16x128 with identity scales (2x matrix-pipe rate, same
//     quantization as R5); plain consecutive-k fp8 layout, same swizzle/schedule.

#define C_DIM 768
#define P_DIM 16384
#define KT 6            // K-tiles (BK=128) : 768/128
#define NJT 16          // j-tiles per block: (P/JSPLIT)/256
#define JSPLIT 4
#define EPSF 1e-8f
#define SCALE 64.0f
#define SC_ONE 0x7F7F7F7F   // E8M0 127 = 2^0 in all 4 bytes

typedef unsigned char u8;
typedef float f32x4 __attribute__((ext_vector_type(4)));
typedef int i32x4 __attribute__((ext_vector_type(4)));
typedef int i32x8 __attribute__((ext_vector_type(8)));

// workspace layout (bytes)
#define OFF_XN   0
#define OFF_SN   25165824UL
#define OFF_INVX 50331648UL
#define OFF_INVS 50397184UL
#define OFF_MAX  50462720UL                 // 4 * 16384 * 4

__device__ __forceinline__ void async_copy16(const void* gsrc, void* ldst) {
    __builtin_amdgcn_global_load_lds(
        (const __attribute__((address_space(1))) void*)gsrc,
        (__attribute__((address_space(3))) void*)ldst,
        16, 0, 0);
}

#define CFENCE() asm volatile("" ::: "memory")
#define BARRIER() { CFENCE(); __builtin_amdgcn_s_barrier(); CFENCE(); }

// --- 1. column L2 norms: inv = SCALE/(||col|| + eps) ---
__global__ void norm_kernel(const float* __restrict__ x, const float* __restrict__ s,
                            float* __restrict__ invx, float* __restrict__ invs) {
    const float4* src = (const float4*)(blockIdx.y == 0 ? x : s);
    float* dst = (blockIdx.y == 0) ? invx : invs;
    int j4 = blockIdx.x * 256 + threadIdx.x;
    float sx = 0.f, sy = 0.f, sz = 0.f, sw = 0.f;
    for (int c = 0; c < C_DIM; ++c) {
        float4 v = src[c * (P_DIM / 4) + j4];
        sx += v.x * v.x; sy += v.y * v.y; sz += v.z * v.z; sw += v.w * v.w;
    }
    int j = j4 * 4;
    dst[j + 0] = SCALE / (sqrtf(sx) + EPSF);
    dst[j + 1] = SCALE / (sqrtf(sy) + EPSF);
    dst[j + 2] = SCALE / (sqrtf(sz) + EPSF);
    dst[j + 3] = SCALE / (sqrtf(sw) + EPSF);
}

// --- 2. transpose [c][p] -> [p][c], normalize*64, cast fp8 e4m3 (plain k order) ---
__global__ void tnorm_kernel(const float* __restrict__ x, const float* __restrict__ s,
                             const float* __restrict__ invx, const float* __restrict__ invs,
                             u8* __restrict__ Xn, u8* __restrict__ Sn) {
    __shared__ float tile[64][65];
    const float* src = blockIdx.z ? s : x;
    const float* inv = blockIdx.z ? invs : invx;
    u8* dst = blockIdx.z ? Sn : Xn;
    int c0 = blockIdx.y * 64;
    int j0 = blockIdx.x * 64;
    int t = threadIdx.x;
    #pragma unroll
    for (int it = 0; it < 16; ++it) {
        int idx = it * 256 + t;
        int cr = idx >> 6, jc = idx & 63;
        tile[cr][jc] = src[(c0 + cr) * P_DIM + j0 + jc];
    }
    __syncthreads();
    #pragma unroll
    for (int it = 0; it < 2; ++it) {
        int item = it * 256 + t;
        int jr = item >> 3;
        int oct = item & 7;
        float iv = inv[j0 + jr];
        float v[8];
        #pragma unroll
        for (int o = 0; o < 8; ++o) v[o] = tile[oct * 8 + o][jr] * iv;
        int lo = __builtin_amdgcn_cvt_pk_fp8_f32(v[0], v[1], 0, false);
        lo = __builtin_amdgcn_cvt_pk_fp8_f32(v[2], v[3], lo, true);
        int hi = __builtin_amdgcn_cvt_pk_fp8_f32(v[4], v[5], 0, false);
        hi = __builtin_amdgcn_cvt_pk_fp8_f32(v[6], v[7], hi, true);
        unsigned long long pk = ((unsigned long long)(unsigned int)hi << 32) | (unsigned int)lo;
        *(unsigned long long*)(dst + (size_t)(j0 + jr) * C_DIM + c0 + oct * 8) = pk;
    }
}

// --- 3. 256x256-tile MX-fp8 GEMM with fused per-row running max ---
// 8 waves (2M x 4N), per-wave 128x64 out; BK=128; one scaled MFMA covers K=128.
// Fragment: lane l -> row l&15, k-chunk l>>4 (32 consecutive bytes = 2 b128 at
// XOR-swizzled 16B blocks (2h+j)^(l&7)). Identity scales (0x7F = 1.0).
__global__ __launch_bounds__(512, 2) void nnfm_gemm_max(
    const u8* __restrict__ Xn, const u8* __restrict__ Sn,
    float* __restrict__ wmax) {
    __shared__ __align__(16) u8 smA[2][256 * 128];
    __shared__ __align__(16) u8 smB[2][256 * 128];

    const int bid = blockIdx.x;
    const int iblk = bid >> 2;
    const int split = bid & 3;
    const int i0 = iblk * 256;
    const int jbase = split * (P_DIM / JSPLIT);

    const int tid = threadIdx.x;
    const int lane = tid & 63;
    const int wid = tid >> 6;
    const int wr = (wid >> 2) * 128;
    const int wc = (wid & 3) * 64;
    const int lm = lane & 15;

    const int srow = wid * 8 + (lane >> 3);
    const int scol = ((lane & 7) ^ (lane >> 3)) * 16;      // bytes
    const int qidx0 = ((2 * (lane >> 4) + 0) ^ (lane & 7)) * 16;
    const int qidx1 = ((2 * (lane >> 4) + 1) ^ (lane & 7)) * 16;

#define STAGE_A(kk_t, buf_t, c) { \
    async_copy16(Xn + (size_t)(i0 + (c) * 64 + srow) * C_DIM + (kk_t) * 128 + scol, \
                 &smA[buf_t][((c) * 64 + wid * 8) * 128]); }

#define STAGE_B(jt_t, kk_t, buf_t, c) { \
    async_copy16(Sn + (size_t)(jbase + (jt_t) * 256 + (c) * 64 + srow) * C_DIM + (kk_t) * 128 + scol, \
                 &smB[buf_t][((c) * 64 + wid * 8) * 128]); }

#define RD_A(QH, BUF) { \
    _Pragma("unroll") \
    for (int m = 0; m < 4; ++m) { \
      i32x4 r0 = *(const i32x4*)&smA[BUF][(wr + (QH) * 64 + m * 16 + lm) * 128 + qidx0]; \
      i32x4 r1 = *(const i32x4*)&smA[BUF][(wr + (QH) * 64 + m * 16 + lm) * 128 + qidx1]; \
      aF[m] = __builtin_shufflevector(r0, r1, 0, 1, 2, 3, 4, 5, 6, 7); \
    } }

#define RD_B(NH, BUF) { \
    _Pragma("unroll") \
    for (int n = 0; n < 2; ++n) { \
      i32x4 r0 = *(const i32x4*)&smB[BUF][(wc + (NH) * 32 + n * 16 + lm) * 128 + qidx0]; \
      i32x4 r1 = *(const i32x4*)&smB[BUF][(wc + (NH) * 32 + n * 16 + lm) * 128 + qidx1]; \
      bF[n] = __builtin_shufflevector(r0, r1, 0, 1, 2, 3, 4, 5, 6, 7); \
    } }

#define MQ(MH, NH, DOZERO, DORMAX) { \
    if (DOZERO) { \
      _Pragma("unroll") \
      for (int m = 0; m < 4; ++m) \
        _Pragma("unroll") \
        for (int n = 0; n < 2; ++n) \
          acc[(MH) * 4 + m][(NH) * 2 + n] = f32x4{0.f, 0.f, 0.f, 0.f}; \
    } \
    __builtin_amdgcn_s_setprio(1); \
    _Pragma("unroll") \
    for (int m = 0; m < 4; ++m) \
      _Pragma("unroll") \
      for (int n = 0; n < 2; ++n) \
        acc[(MH) * 4 + m][(NH) * 2 + n] = __builtin_amdgcn_mfma_scale_f32_16x16x128_f8f6f4( \
            aF[m], bF[n], acc[(MH) * 4 + m][(NH) * 2 + n], 0, 0, 0, SC_ONE, 0, SC_ONE); \
    __builtin_amdgcn_s_setprio(0); \
    if (DORMAX) { \
      _Pragma("unroll") \
      for (int m = 0; m < 4; ++m) \
        _Pragma("unroll") \
        for (int r = 0; r < 4; ++r) \
          rmax[(MH) * 4 + m][r] = fmaxf(rmax[(MH) * 4 + m][r], \
              fmaxf(acc[(MH) * 4 + m][(NH) * 2 + 0][r], acc[(MH) * 4 + m][(NH) * 2 + 1][r])); \
    } }

    f32x4 acc[8][4];
    float rmax[8][4];
    i32x8 aF[4], bF[2];
    #pragma unroll
    for (int m = 0; m < 8; ++m)
        #pragma unroll
        for (int r = 0; r < 4; ++r) rmax[m][r] = -3.0e38f;

    // prologue: A(0)c0-3, B(0)c0-3, A(1)c0,c1 (10 loads); oldest 8 -> vmcnt(2)
    STAGE_A(0, 0, 0); STAGE_A(0, 0, 1); STAGE_A(0, 0, 2); STAGE_A(0, 0, 3);
    STAGE_B(0, 0, 0, 0); STAGE_B(0, 0, 0, 1); STAGE_B(0, 0, 0, 2); STAGE_B(0, 0, 0, 3);
    STAGE_A(1, 1, 0); STAGE_A(1, 1, 1);
    asm volatile("s_waitcnt vmcnt(2)" ::: "memory");
    BARRIER();

    for (int jt = 0; jt < NJT; ++jt) {
        for (int kk = 0; kk < KT; ++kk) {
            const int buf = kk & 1;
            int kk1 = kk + 1, jt1 = jt;
            if (kk1 == KT) { kk1 = 0; jt1 = (jt + 1) & (NJT - 1); }
            int kk2 = kk + 2, jt2 = jt;
            if (kk2 >= KT) { kk2 -= KT; jt2 = (jt + 1) & (NJT - 1); }
            const bool z = (kk == 0), rx = (kk == KT - 1);

            // p0: quad(0,0)
            RD_A(0, buf) RD_B(0, buf)
            STAGE_A(kk1, buf ^ 1, 2); STAGE_A(kk1, buf ^ 1, 3);
            BARRIER();
            MQ(0, 0, z, rx)
            BARRIER();
            // p1: quad(0,1)
            RD_B(1, buf)
            STAGE_B(jt1, kk1, buf ^ 1, 0); STAGE_B(jt1, kk1, buf ^ 1, 1);
            BARRIER();
            MQ(0, 1, z, rx)
            BARRIER();
            // p2: quad(1,1)
            RD_A(1, buf)
            STAGE_B(jt1, kk1, buf ^ 1, 2); STAGE_B(jt1, kk1, buf ^ 1, 3);
            BARRIER();
            MQ(1, 1, z, rx)
            BARRIER();
            // p3: quad(1,0)
            RD_B(0, buf)
            STAGE_A(kk2, buf, 0); STAGE_A(kk2, buf, 1);
            BARRIER();
            MQ(1, 0, z, rx)
            asm volatile("s_waitcnt vmcnt(2)" ::: "memory");
            BARRIER();
        }
    }

    // epilogue: drain all DMA before reusing LDS
    asm volatile("s_waitcnt vmcnt(0) lgkmcnt(0)" ::: "memory");
    BARRIER();

    float* red = (float*)&smA[0][0];   // [4 col-waves][256 rows]
    #pragma unroll
    for (int m8 = 0; m8 < 8; ++m8)
        #pragma unroll
        for (int r = 0; r < 4; ++r) {
            float v = rmax[m8][r];
            v = fmaxf(v, __shfl_xor(v, 1));
            v = fmaxf(v, __shfl_xor(v, 2));
            v = fmaxf(v, __shfl_xor(v, 4));
            v = fmaxf(v, __shfl_xor(v, 8));
            if (lm == 0) {
                const int row_l = wr + (m8 >> 2) * 64 + (m8 & 3) * 16 + (lane >> 4) * 4 + r;
                red[(wid & 3) * 256 + row_l] = v;
            }
        }
    BARRIER();
    if (tid < 256) {
        float v = fmaxf(fmaxf(red[tid], red[256 + tid]),
                        fmaxf(red[512 + tid], red[768 + tid]));
        wmax[(size_t)split * P_DIM + i0 + tid] = v;
    }
}

// --- 4. loss = mean(1 - max/SCALE^2) ---
__global__ void final_reduce(const float* __restrict__ wmax, float* __restrict__ out) {
    __shared__ float red[256];
    int t = threadIdx.x;
    const float isc = 1.0f / (SCALE * SCALE);
    float sum = 0.f;
    for (int i = t; i < P_DIM; i += 256) {
        float m = wmax[i];
        #pragma unroll
        for (int sp = 1; sp < 4; ++sp) m = fmaxf(m, wmax[(size_t)sp * P_DIM + i]);
        sum += 1.0f - m * isc;
    }
    red[t] = sum;
    __syncthreads();
    for (int st = 128; st > 0; st >>= 1) {
        if (t < st) red[t] += red[t + st];
        __syncthreads();
    }
    if (t == 0) out[0] = red[0] * (1.0f / (float)P_DIM);
}

extern "C" void kernel_launch(void* const* d_in, const int* in_sizes, int n_in,
                              void* d_out, int out_size, void* d_ws, size_t ws_size,
                              hipStream_t stream) {
    const float* x = (const float*)d_in[0];
    const float* s = (const float*)d_in[1];
    float* out = (float*)d_out;
    char* ws = (char*)d_ws;

    u8* Xn = (u8*)(ws + OFF_XN);
    u8* Sn = (u8*)(ws + OFF_SN);
    float* invx = (float*)(ws + OFF_INVX);
    float* invs = (float*)(ws + OFF_INVS);
    float* wmax = (float*)(ws + OFF_MAX);

    norm_kernel<<<dim3(16, 2), 256, 0, stream>>>(x, s, invx, invs);
    tnorm_kernel<<<dim3(256, 12, 2), 256, 0, stream>>>(x, s, invx, invs, Xn, Sn);
    nnfm_gemm_max<<<dim3((P_DIM / 256) * JSPLIT), 512, 0, stream>>>(Xn, Sn, wmax);
    final_reduce<<<1, 256, 0, stream>>>(wmax, out);
}

// Round 7
// 379.271 us; speedup vs baseline: 1.4099x; 1.4099x over previous
//
#include <hip/hip_runtime.h>
#include <math.h>

// NNFM loss on MI355X.
// loss = mean_i (1 - max_j (xhat_i . shat_j)),  xhat/shat = column-normalized feats.
// R2: XOR-swizzled LDS -> bank conflicts 1.5e8 -> 0 (475us).
// R3: 256^2 tile, 8 waves, 4-phase schedule + counted vmcnt + setprio (465us).
// R4: double-set read-ahead -> VGPR spill, reverted.
// R5: fp8 e4m3, BK=128 -> 320us GEMM, MfmaUtil 55%.
// R6: MX-scaled 16x16x128 -> acc forced out of AGPRs -> 631MB scratch spill. Reverted.
// R7: i8 MFMA 16x16x64 (2x K, ~1.9x rate, 4-VGPR operands, acc stays in AGPR).
//     Same LDS layout/swizzle/schedule as R5; i8 quant at scale 256, exact i32 accum.

#define C_DIM 768
#define P_DIM 16384
#define KT 6            // K-tiles (BK=128) : 768/128
#define NJT 16          // j-tiles per block: (P/JSPLIT)/256
#define JSPLIT 4
#define EPSF 1e-8f
#define QSCALE 256.0f

typedef unsigned char u8;
typedef int i32x4 __attribute__((ext_vector_type(4)));

// workspace layout (bytes)
#define OFF_XN   0
#define OFF_SN   25165824UL
#define OFF_INVX 50331648UL
#define OFF_INVS 50397184UL
#define OFF_MAX  50462720UL                 // 4 * 16384 * 4

__device__ __forceinline__ void async_copy16(const void* gsrc, void* ldst) {
    __builtin_amdgcn_global_load_lds(
        (const __attribute__((address_space(1))) void*)gsrc,
        (__attribute__((address_space(3))) void*)ldst,
        16, 0, 0);
}

#define CFENCE() asm volatile("" ::: "memory")
#define BARRIER() { CFENCE(); __builtin_amdgcn_s_barrier(); CFENCE(); }

// --- 1. column L2 norms: inv = QSCALE/(||col|| + eps) ---
__global__ void norm_kernel(const float* __restrict__ x, const float* __restrict__ s,
                            float* __restrict__ invx, float* __restrict__ invs) {
    const float4* src = (const float4*)(blockIdx.y == 0 ? x : s);
    float* dst = (blockIdx.y == 0) ? invx : invs;
    int j4 = blockIdx.x * 256 + threadIdx.x;
    float sx = 0.f, sy = 0.f, sz = 0.f, sw = 0.f;
    for (int c = 0; c < C_DIM; ++c) {
        float4 v = src[c * (P_DIM / 4) + j4];
        sx += v.x * v.x; sy += v.y * v.y; sz += v.z * v.z; sw += v.w * v.w;
    }
    int j = j4 * 4;
    dst[j + 0] = QSCALE / (sqrtf(sx) + EPSF);
    dst[j + 1] = QSCALE / (sqrtf(sy) + EPSF);
    dst[j + 2] = QSCALE / (sqrtf(sz) + EPSF);
    dst[j + 3] = QSCALE / (sqrtf(sw) + EPSF);
}

// --- 2. transpose [c][p] -> [p][c], normalize*256, round to int8 ---
__global__ void tnorm_kernel(const float* __restrict__ x, const float* __restrict__ s,
                             const float* __restrict__ invx, const float* __restrict__ invs,
                             u8* __restrict__ Xn, u8* __restrict__ Sn) {
    __shared__ float tile[64][65];
    const float* src = blockIdx.z ? s : x;
    const float* inv = blockIdx.z ? invs : invx;
    u8* dst = blockIdx.z ? Sn : Xn;
    int c0 = blockIdx.y * 64;
    int j0 = blockIdx.x * 64;
    int t = threadIdx.x;
    #pragma unroll
    for (int it = 0; it < 16; ++it) {
        int idx = it * 256 + t;
        int cr = idx >> 6, jc = idx & 63;
        tile[cr][jc] = src[(c0 + cr) * P_DIM + j0 + jc];
    }
    __syncthreads();
    #pragma unroll
    for (int it = 0; it < 2; ++it) {
        int item = it * 256 + t;
        int jr = item >> 3;
        int oct = item & 7;
        float iv = inv[j0 + jr];
        unsigned long long pk = 0;
        #pragma unroll
        for (int o = 0; o < 8; ++o) {
            float v = tile[oct * 8 + o][jr] * iv;
            v = fminf(fmaxf(v, -127.0f), 127.0f);
            int q = (int)rintf(v);
            pk |= ((unsigned long long)(unsigned)(q & 0xFF)) << (8 * o);
        }
        *(unsigned long long*)(dst + (size_t)(j0 + jr) * C_DIM + c0 + oct * 8) = pk;
    }
}

// --- 3. 256x256-tile i8 GEMM with fused per-row running max ---
// 8 waves (2M x 4N), per-wave 128x64 out; BK=128 = 2 MFMA k-steps (K=64 each).
// Fragment: lane l -> row l&15, k-bytes [(ks*4 + (l>>4))^swz]*16; one b128 each.
__global__ __launch_bounds__(512, 2) void nnfm_gemm_max(
    const u8* __restrict__ Xn, const u8* __restrict__ Sn,
    float* __restrict__ wmax) {
    __shared__ __align__(16) u8 smA[2][256 * 128];
    __shared__ __align__(16) u8 smB[2][256 * 128];

    const int bid = blockIdx.x;
    const int iblk = bid >> 2;
    const int split = bid & 3;
    const int i0 = iblk * 256;
    const int jbase = split * (P_DIM / JSPLIT);

    const int tid = threadIdx.x;
    const int lane = tid & 63;
    const int wid = tid >> 6;
    const int wr = (wid >> 2) * 128;
    const int wc = (wid & 3) * 64;
    const int lm = lane & 15;

    const int srow = wid * 8 + (lane >> 3);
    const int scol = ((lane & 7) ^ (lane >> 3)) * 16;      // bytes
    const int kidx0 = (((lane >> 4) + 0) ^ (lane & 7)) * 16;
    const int kidx1 = (((lane >> 4) + 4) ^ (lane & 7)) * 16;

#define STAGE_A(kk_t, buf_t, c) { \
    async_copy16(Xn + (size_t)(i0 + (c) * 64 + srow) * C_DIM + (kk_t) * 128 + scol, \
                 &smA[buf_t][((c) * 64 + wid * 8) * 128]); }

#define STAGE_B(jt_t, kk_t, buf_t, c) { \
    async_copy16(Sn + (size_t)(jbase + (jt_t) * 256 + (c) * 64 + srow) * C_DIM + (kk_t) * 128 + scol, \
                 &smB[buf_t][((c) * 64 + wid * 8) * 128]); }

#define RD_A(QH, BUF) { \
    _Pragma("unroll") \
    for (int m = 0; m < 4; ++m) { \
      aF[m][0] = *(const i32x4*)&smA[BUF][(wr + (QH) * 64 + m * 16 + lm) * 128 + kidx0]; \
      aF[m][1] = *(const i32x4*)&smA[BUF][(wr + (QH) * 64 + m * 16 + lm) * 128 + kidx1]; \
    } }

#define RD_B(NH, BUF) { \
    _Pragma("unroll") \
    for (int n = 0; n < 2; ++n) { \
      bF[n][0] = *(const i32x4*)&smB[BUF][(wc + (NH) * 32 + n * 16 + lm) * 128 + kidx0]; \
      bF[n][1] = *(const i32x4*)&smB[BUF][(wc + (NH) * 32 + n * 16 + lm) * 128 + kidx1]; \
    } }

#define MQ(MH, NH, DOZERO, DORMAX) { \
    if (DOZERO) { \
      _Pragma("unroll") \
      for (int m = 0; m < 4; ++m) \
        _Pragma("unroll") \
        for (int n = 0; n < 2; ++n) \
          acc[(MH) * 4 + m][(NH) * 2 + n] = i32x4{0, 0, 0, 0}; \
    } \
    __builtin_amdgcn_s_setprio(1); \
    _Pragma("unroll") \
    for (int ks = 0; ks < 2; ++ks) \
      _Pragma("unroll") \
      for (int m = 0; m < 4; ++m) \
        _Pragma("unroll") \
        for (int n = 0; n < 2; ++n) \
          acc[(MH) * 4 + m][(NH) * 2 + n] = __builtin_amdgcn_mfma_i32_16x16x64_i8( \
              aF[m][ks], bF[n][ks], acc[(MH) * 4 + m][(NH) * 2 + n], 0, 0, 0); \
    __builtin_amdgcn_s_setprio(0); \
    if (DORMAX) { \
      _Pragma("unroll") \
      for (int m = 0; m < 4; ++m) \
        _Pragma("unroll") \
        for (int r = 0; r < 4; ++r) { \
          int a0 = acc[(MH) * 4 + m][(NH) * 2 + 0][r]; \
          int a1 = acc[(MH) * 4 + m][(NH) * 2 + 1][r]; \
          int mx = a0 > a1 ? a0 : a1; \
          if (mx > rmax[(MH) * 4 + m][r]) rmax[(MH) * 4 + m][r] = mx; \
        } \
    } }

    i32x4 acc[8][4];
    int rmax[8][4];
    i32x4 aF[4][2], bF[2][2];
    #pragma unroll
    for (int m = 0; m < 8; ++m)
        #pragma unroll
        for (int r = 0; r < 4; ++r) rmax[m][r] = (int)0x80000000;

    // prologue: A(0)c0-3, B(0)c0-3, A(1)c0,c1 (10 loads); oldest 8 -> vmcnt(2)
    STAGE_A(0, 0, 0); STAGE_A(0, 0, 1); STAGE_A(0, 0, 2); STAGE_A(0, 0, 3);
    STAGE_B(0, 0, 0, 0); STAGE_B(0, 0, 0, 1); STAGE_B(0, 0, 0, 2); STAGE_B(0, 0, 0, 3);
    STAGE_A(1, 1, 0); STAGE_A(1, 1, 1);
    asm volatile("s_waitcnt vmcnt(2)" ::: "memory");
    BARRIER();

    for (int jt = 0; jt < NJT; ++jt) {
        for (int kk = 0; kk < KT; ++kk) {
            const int buf = kk & 1;
            int kk1 = kk + 1, jt1 = jt;
            if (kk1 == KT) { kk1 = 0; jt1 = (jt + 1) & (NJT - 1); }
            int kk2 = kk + 2, jt2 = jt;
            if (kk2 >= KT) { kk2 -= KT; jt2 = (jt + 1) & (NJT - 1); }
            const bool z = (kk == 0), rx = (kk == KT - 1);

            // p0: quad(0,0)
            RD_A(0, buf) RD_B(0, buf)
            STAGE_A(kk1, buf ^ 1, 2); STAGE_A(kk1, buf ^ 1, 3);
            BARRIER();
            MQ(0, 0, z, rx)
            BARRIER();
            // p1: quad(0,1)
            RD_B(1, buf)
            STAGE_B(jt1, kk1, buf ^ 1, 0); STAGE_B(jt1, kk1, buf ^ 1, 1);
            BARRIER();
            MQ(0, 1, z, rx)
            BARRIER();
            // p2: quad(1,1)
            RD_A(1, buf)
            STAGE_B(jt1, kk1, buf ^ 1, 2); STAGE_B(jt1, kk1, buf ^ 1, 3);
            BARRIER();
            MQ(1, 1, z, rx)
            BARRIER();
            // p3: quad(1,0)
            RD_B(0, buf)
            STAGE_A(kk2, buf, 0); STAGE_A(kk2, buf, 1);
            BARRIER();
            MQ(1, 0, z, rx)
            asm volatile("s_waitcnt vmcnt(2)" ::: "memory");
            BARRIER();
        }
    }

    // epilogue: drain all DMA before reusing LDS
    asm volatile("s_waitcnt vmcnt(0) lgkmcnt(0)" ::: "memory");
    BARRIER();

    const float isc = 1.0f / (QSCALE * QSCALE);
    float* red = (float*)&smA[0][0];   // [4 col-waves][256 rows]
    #pragma unroll
    for (int m8 = 0; m8 < 8; ++m8)
        #pragma unroll
        for (int r = 0; r < 4; ++r) {
            int v = rmax[m8][r];
            int o;
            o = __shfl_xor(v, 1); if (o > v) v = o;
            o = __shfl_xor(v, 2); if (o > v) v = o;
            o = __shfl_xor(v, 4); if (o > v) v = o;
            o = __shfl_xor(v, 8); if (o > v) v = o;
            if (lm == 0) {
                const int row_l = wr + (m8 >> 2) * 64 + (m8 & 3) * 16 + (lane >> 4) * 4 + r;
                red[(wid & 3) * 256 + row_l] = (float)v * isc;
            }
        }
    BARRIER();
    if (tid < 256) {
        float v = fmaxf(fmaxf(red[tid], red[256 + tid]),
                        fmaxf(red[512 + tid], red[768 + tid]));
        wmax[(size_t)split * P_DIM + i0 + tid] = v;
    }
}

// --- 4. loss = mean(1 - max over 4 partials) ---
__global__ void final_reduce(const float* __restrict__ wmax, float* __restrict__ out) {
    __shared__ float red[256];
    int t = threadIdx.x;
    float sum = 0.f;
    for (int i = t; i < P_DIM; i += 256) {
        float m = wmax[i];
        #pragma unroll
        for (int sp = 1; sp < 4; ++sp) m = fmaxf(m, wmax[(size_t)sp * P_DIM + i]);
        sum += 1.0f - m;
    }
    red[t] = sum;
    __syncthreads();
    for (int st = 128; st > 0; st >>= 1) {
        if (t < st) red[t] += red[t + st];
        __syncthreads();
    }
    if (t == 0) out[0] = red[0] * (1.0f / (float)P_DIM);
}

extern "C" void kernel_launch(void* const* d_in, const int* in_sizes, int n_in,
                              void* d_out, int out_size, void* d_ws, size_t ws_size,
                              hipStream_t stream) {
    const float* x = (const float*)d_in[0];
    const float* s = (const float*)d_in[1];
    float* out = (float*)d_out;
    char* ws = (char*)d_ws;

    u8* Xn = (u8*)(ws + OFF_XN);
    u8* Sn = (u8*)(ws + OFF_SN);
    float* invx = (float*)(ws + OFF_INVX);
    float* invs = (float*)(ws + OFF_INVS);
    float* wmax = (float*)(ws + OFF_MAX);

    norm_kernel<<<dim3(16, 2), 256, 0, stream>>>(x, s, invx, invs);
    tnorm_kernel<<<dim3(256, 12, 2), 256, 0, stream>>>(x, s, invx, invs, Xn, Sn);
    nnfm_gemm_max<<<dim3((P_DIM / 256) * JSPLIT), 512, 0, stream>>>(Xn, Sn, wmax);
    final_reduce<<<1, 256, 0, stream>>>(wmax, out);
}

// Round 8
// 302.944 us; speedup vs baseline: 1.7651x; 1.2520x over previous
//
#include <hip/hip_runtime.h>
#include <math.h>

// NNFM loss on MI355X.
// loss = mean_i (1 - max_j (xhat_i . shat_j)),  xhat/shat = column-normalized feats.
// R2: XOR-swizzled LDS -> bank conflicts 0 (475us).
// R3: 256^2 tile 8-wave phase schedule (465us). R4: reg-double-buffer spill, reverted.
// R5: fp8 BK=128 -> 320us. R6: MX-scale -> spill, reverted.
// R7: i8 16x16x64 -> 327us, MfmaUtil 26% -> NOT MFMA-bound: barrier-lockstep
//     serializes LDS-read phase vs MFMA phase (105us MFMA + 90us LDS + stalls).
// R8: 128^2 tile, 4 waves, LDS 64KB -> 2 independent blocks/CU so one block's
//     LDS phase overlaps the other's MFMA phase (m97/m114 mechanism).

#define C_DIM 768
#define P_DIM 16384
#define KT 6            // K-tiles (BK=128) : 768/128
#define NJT 32          // j-tiles per block: 4096/128
#define JSPLIT 4
#define EPSF 1e-8f
#define QSCALE 256.0f

typedef unsigned char u8;
typedef int i32x4 __attribute__((ext_vector_type(4)));

// workspace layout (bytes)
#define OFF_XN   0
#define OFF_SN   25165824UL
#define OFF_INVX 50331648UL
#define OFF_INVS 50397184UL
#define OFF_MAX  50462720UL                 // 4 * 16384 * 4

__device__ __forceinline__ void async_copy16(const void* gsrc, void* ldst) {
    __builtin_amdgcn_global_load_lds(
        (const __attribute__((address_space(1))) void*)gsrc,
        (__attribute__((address_space(3))) void*)ldst,
        16, 0, 0);
}

#define CFENCE() asm volatile("" ::: "memory")
#define BARRIER() { CFENCE(); __builtin_amdgcn_s_barrier(); CFENCE(); }

// --- 1. column L2 norms: inv = QSCALE/(||col|| + eps) ---
__global__ void norm_kernel(const float* __restrict__ x, const float* __restrict__ s,
                            float* __restrict__ invx, float* __restrict__ invs) {
    const float4* src = (const float4*)(blockIdx.y == 0 ? x : s);
    float* dst = (blockIdx.y == 0) ? invx : invs;
    int j4 = blockIdx.x * 256 + threadIdx.x;
    float sx = 0.f, sy = 0.f, sz = 0.f, sw = 0.f;
    for (int c = 0; c < C_DIM; ++c) {
        float4 v = src[c * (P_DIM / 4) + j4];
        sx += v.x * v.x; sy += v.y * v.y; sz += v.z * v.z; sw += v.w * v.w;
    }
    int j = j4 * 4;
    dst[j + 0] = QSCALE / (sqrtf(sx) + EPSF);
    dst[j + 1] = QSCALE / (sqrtf(sy) + EPSF);
    dst[j + 2] = QSCALE / (sqrtf(sz) + EPSF);
    dst[j + 3] = QSCALE / (sqrtf(sw) + EPSF);
}

// --- 2. transpose [c][p] -> [p][c], normalize*256, round to int8 ---
__global__ void tnorm_kernel(const float* __restrict__ x, const float* __restrict__ s,
                             const float* __restrict__ invx, const float* __restrict__ invs,
                             u8* __restrict__ Xn, u8* __restrict__ Sn) {
    __shared__ float tile[64][65];
    const float* src = blockIdx.z ? s : x;
    const float* inv = blockIdx.z ? invs : invx;
    u8* dst = blockIdx.z ? Sn : Xn;
    int c0 = blockIdx.y * 64;
    int j0 = blockIdx.x * 64;
    int t = threadIdx.x;
    #pragma unroll
    for (int it = 0; it < 16; ++it) {
        int idx = it * 256 + t;
        int cr = idx >> 6, jc = idx & 63;
        tile[cr][jc] = src[(c0 + cr) * P_DIM + j0 + jc];
    }
    __syncthreads();
    #pragma unroll
    for (int it = 0; it < 2; ++it) {
        int item = it * 256 + t;
        int jr = item >> 3;
        int oct = item & 7;
        float iv = inv[j0 + jr];
        unsigned long long pk = 0;
        #pragma unroll
        for (int o = 0; o < 8; ++o) {
            float v = tile[oct * 8 + o][jr] * iv;
            v = fminf(fmaxf(v, -127.0f), 127.0f);
            int q = (int)rintf(v);
            pk |= ((unsigned long long)(unsigned)(q & 0xFF)) << (8 * o);
        }
        *(unsigned long long*)(dst + (size_t)(j0 + jr) * C_DIM + c0 + oct * 8) = pk;
    }
}

// --- 3. 128x128-tile i8 GEMM, 4 waves (2M x 2N), per-wave 64x64; 2 blocks/CU ---
// 2 phases per K-tile (ks split). Stage: p0 -> B(t+1) into bufB^1;
// p1 -> A(t+2) into live bufA (after A's last reads; pattern proven R5-R7).
// vmcnt(4) once per K-tile: outstanding = B(t+1) 4 + A(t+2) 4 -> waits B(t+1).
__global__ __launch_bounds__(256, 2) void nnfm_gemm_max(
    const u8* __restrict__ Xn, const u8* __restrict__ Sn,
    float* __restrict__ wmax) {
    __shared__ __align__(16) u8 smA[2][128 * 128];
    __shared__ __align__(16) u8 smB[2][128 * 128];

    const int bid = blockIdx.x;
    const int iblk = bid >> 2;
    const int split = bid & 3;
    const int i0 = iblk * 128;
    const int jbase = split * (P_DIM / JSPLIT);

    const int tid = threadIdx.x;
    const int lane = tid & 63;
    const int wid = tid >> 6;
    const int wrow = (wid >> 1) * 64;
    const int wcol = (wid & 1) * 64;
    const int lm = lane & 15;

    const int srow = wid * 8 + (lane >> 3);                // + c*32 during staging
    const int scol = ((lane & 7) ^ (lane >> 3)) * 16;      // bytes, swizzled source col
    const int kidx0 = (((lane >> 4) + 0) ^ (lane & 7)) * 16;
    const int kidx1 = (((lane >> 4) + 4) ^ (lane & 7)) * 16;

#define STAGE_A(kk_t) { \
    _Pragma("unroll") \
    for (int c = 0; c < 4; ++c) \
      async_copy16(Xn + (size_t)(i0 + c * 32 + srow) * C_DIM + (kk_t) * 128 + scol, \
                   &smA[((kk_t) & 1)][(c * 32 + wid * 8) * 128]); }

#define STAGE_B(jt_t, kk_t) { \
    _Pragma("unroll") \
    for (int c = 0; c < 4; ++c) \
      async_copy16(Sn + (size_t)(jbase + (jt_t) * 128 + c * 32 + srow) * C_DIM + (kk_t) * 128 + scol, \
                   &smB[((kk_t) & 1)][(c * 32 + wid * 8) * 128]); }

#define RD_AB(KIDX, BUF) { \
    _Pragma("unroll") \
    for (int m = 0; m < 4; ++m) \
      aF[m] = *(const i32x4*)&smA[BUF][(wrow + m * 16 + lm) * 128 + (KIDX)]; \
    _Pragma("unroll") \
    for (int n = 0; n < 4; ++n) \
      bF[n] = *(const i32x4*)&smB[BUF][(wcol + n * 16 + lm) * 128 + (KIDX)]; }

#define MFMA16(DOZERO) { \
    if (DOZERO) { \
      _Pragma("unroll") \
      for (int m = 0; m < 4; ++m) \
        _Pragma("unroll") \
        for (int n = 0; n < 4; ++n) \
          acc[m][n] = i32x4{0, 0, 0, 0}; \
    } \
    __builtin_amdgcn_s_setprio(1); \
    _Pragma("unroll") \
    for (int m = 0; m < 4; ++m) \
      _Pragma("unroll") \
      for (int n = 0; n < 4; ++n) \
        acc[m][n] = __builtin_amdgcn_mfma_i32_16x16x64_i8(aF[m], bF[n], acc[m][n], 0, 0, 0); \
    __builtin_amdgcn_s_setprio(0); }

    i32x4 acc[4][4];
    int rmax[4][4];
    i32x4 aF[4], bF[4];
    #pragma unroll
    for (int m = 0; m < 4; ++m)
        #pragma unroll
        for (int r = 0; r < 4; ++r) rmax[m][r] = (int)0x80000000;

    // prologue: A(0), B(0), A(1) = 12 loads; first 8 must land -> vmcnt(4)
    STAGE_A(0);
    STAGE_B(0, 0);
    STAGE_A(1);
    asm volatile("s_waitcnt vmcnt(4)" ::: "memory");
    BARRIER();

    for (int jt = 0; jt < NJT; ++jt) {
        for (int kk = 0; kk < KT; ++kk) {
            const int buf = kk & 1;
            int kk1 = kk + 1, jt1 = jt;
            if (kk1 == KT) { kk1 = 0; jt1 = (jt + 1) & (NJT - 1); }
            int kk2 = kk + 2;
            if (kk2 >= KT) kk2 -= KT;
            const bool z = (kk == 0), rx = (kk == KT - 1);

            // p0: ks=0
            RD_AB(kidx0, buf)
            STAGE_B(jt1, kk1)
            BARRIER();
            MFMA16(z)
            BARRIER();
            // p1: ks=1
            RD_AB(kidx1, buf)
            STAGE_A(kk2)                  // into live bufA, after its last reads
            BARRIER();
            MFMA16(false)
            if (rx) {
                #pragma unroll
                for (int m = 0; m < 4; ++m)
                    #pragma unroll
                    for (int r = 0; r < 4; ++r) {
                        int mx = acc[m][0][r];
                        #pragma unroll
                        for (int n = 1; n < 4; ++n)
                            if (acc[m][n][r] > mx) mx = acc[m][n][r];
                        if (mx > rmax[m][r]) rmax[m][r] = mx;
                    }
            }
            asm volatile("s_waitcnt vmcnt(4)" ::: "memory");
            BARRIER();
        }
    }

    // epilogue: drain all DMA before reusing LDS
    asm volatile("s_waitcnt vmcnt(0) lgkmcnt(0)" ::: "memory");
    BARRIER();

    const float isc = 1.0f / (QSCALE * QSCALE);
    float* red = (float*)&smA[0][0];   // [2 col-waves][128 rows]
    #pragma unroll
    for (int m = 0; m < 4; ++m)
        #pragma unroll
        for (int r = 0; r < 4; ++r) {
            int v = rmax[m][r];
            int o;
            o = __shfl_xor(v, 1); if (o > v) v = o;
            o = __shfl_xor(v, 2); if (o > v) v = o;
            o = __shfl_xor(v, 4); if (o > v) v = o;
            o = __shfl_xor(v, 8); if (o > v) v = o;
            if (lm == 0) {
                const int row_l = wrow + m * 16 + (lane >> 4) * 4 + r;
                red[(wid & 1) * 128 + row_l] = (float)v * isc;
            }
        }
    BARRIER();
    if (tid < 128) {
        wmax[(size_t)split * P_DIM + i0 + tid] = fmaxf(red[tid], red[128 + tid]);
    }
}

// --- 4. loss = mean(1 - max over 4 partials) ---
__global__ void final_reduce(const float* __restrict__ wmax, float* __restrict__ out) {
    __shared__ float red[256];
    int t = threadIdx.x;
    float sum = 0.f;
    for (int i = t; i < P_DIM; i += 256) {
        float m = wmax[i];
        #pragma unroll
        for (int sp = 1; sp < 4; ++sp) m = fmaxf(m, wmax[(size_t)sp * P_DIM + i]);
        sum += 1.0f - m;
    }
    red[t] = sum;
    __syncthreads();
    for (int st = 128; st > 0; st >>= 1) {
        if (t < st) red[t] += red[t + st];
        __syncthreads();
    }
    if (t == 0) out[0] = red[0] * (1.0f / (float)P_DIM);
}

extern "C" void kernel_launch(void* const* d_in, const int* in_sizes, int n_in,
                              void* d_out, int out_size, void* d_ws, size_t ws_size,
                              hipStream_t stream) {
    const float* x = (const float*)d_in[0];
    const float* s = (const float*)d_in[1];
    float* out = (float*)d_out;
    char* ws = (char*)d_ws;

    u8* Xn = (u8*)(ws + OFF_XN);
    u8* Sn = (u8*)(ws + OFF_SN);
    float* invx = (float*)(ws + OFF_INVX);
    float* invs = (float*)(ws + OFF_INVS);
    float* wmax = (float*)(ws + OFF_MAX);

    norm_kernel<<<dim3(16, 2), 256, 0, stream>>>(x, s, invx, invs);
    tnorm_kernel<<<dim3(256, 12, 2), 256, 0, stream>>>(x, s, invx, invs, Xn, Sn);
    nnfm_gemm_max<<<dim3((P_DIM / 128) * JSPLIT), 256, 0, stream>>>(Xn, Sn, wmax);
    final_reduce<<<1, 256, 0, stream>>>(wmax, out);
}

// Round 9
// 295.967 us; speedup vs baseline: 1.8067x; 1.0236x over previous
//
#include <hip/hip_runtime.h>
#include <math.h>

// NNFM loss on MI355X.
// loss = mean_i (1 - max_j (xhat_i . shat_j)),  xhat/shat = column-normalized feats.
// R2: XOR-swizzle -> 0 conflicts. R3: 256^2 8-wave phases. R4: reg-dbuf spill (rev).
// R5: fp8 BK=128 320us. R6: MX-scale spill (rev). R7: i8 16x16x64 327us (lockstep wall).
// R8: 128^2 4-wave 64KB LDS -> 2 blocks/CU overlap -> 239us GEMM.
// R9: (a) merged single phase per K-tile: 1 barrier pair (was 2), 32-MFMA cluster;
//     (b) XCD swizzle: each XCD owns one j-split -> B panel (3MB) L2-resident
//         (FETCH was 767MB for 25MB inputs); (c) norm_kernel grid 32->128 blocks.

#define C_DIM 768
#define P_DIM 16384
#define KT 6            // K-tiles (BK=128) : 768/128
#define NJT 32          // j-tiles per block: 4096/128
#define JSPLIT 4
#define EPSF 1e-8f
#define QSCALE 256.0f

typedef unsigned char u8;
typedef int i32x4 __attribute__((ext_vector_type(4)));

// workspace layout (bytes)
#define OFF_XN   0
#define OFF_SN   25165824UL
#define OFF_INVX 50331648UL
#define OFF_INVS 50397184UL
#define OFF_MAX  50462720UL                 // 4 * 16384 * 4

__device__ __forceinline__ void async_copy16(const void* gsrc, void* ldst) {
    __builtin_amdgcn_global_load_lds(
        (const __attribute__((address_space(1))) void*)gsrc,
        (__attribute__((address_space(3))) void*)ldst,
        16, 0, 0);
}

#define CFENCE() asm volatile("" ::: "memory")
#define BARRIER() { CFENCE(); __builtin_amdgcn_s_barrier(); CFENCE(); }

// --- 1. column L2 norms: inv = QSCALE/(||col|| + eps); one thread per column ---
__global__ void norm_kernel(const float* __restrict__ x, const float* __restrict__ s,
                            float* __restrict__ invx, float* __restrict__ invs) {
    const float* src = blockIdx.y == 0 ? x : s;
    float* dst = (blockIdx.y == 0) ? invx : invs;
    int j = blockIdx.x * 256 + threadIdx.x;        // 0..16383
    float sum = 0.f;
    for (int c = 0; c < C_DIM; ++c) {
        float v = src[(size_t)c * P_DIM + j];
        sum += v * v;
    }
    dst[j] = QSCALE / (sqrtf(sum) + EPSF);
}

// --- 2. transpose [c][p] -> [p][c], normalize*256, round to int8 ---
__global__ void tnorm_kernel(const float* __restrict__ x, const float* __restrict__ s,
                             const float* __restrict__ invx, const float* __restrict__ invs,
                             u8* __restrict__ Xn, u8* __restrict__ Sn) {
    __shared__ float tile[64][65];
    const float* src = blockIdx.z ? s : x;
    const float* inv = blockIdx.z ? invs : invx;
    u8* dst = blockIdx.z ? Sn : Xn;
    int c0 = blockIdx.y * 64;
    int j0 = blockIdx.x * 64;
    int t = threadIdx.x;
    #pragma unroll
    for (int it = 0; it < 16; ++it) {
        int idx = it * 256 + t;
        int cr = idx >> 6, jc = idx & 63;
        tile[cr][jc] = src[(c0 + cr) * P_DIM + j0 + jc];
    }
    __syncthreads();
    #pragma unroll
    for (int it = 0; it < 2; ++it) {
        int item = it * 256 + t;
        int jr = item >> 3;
        int oct = item & 7;
        float iv = inv[j0 + jr];
        unsigned long long pk = 0;
        #pragma unroll
        for (int o = 0; o < 8; ++o) {
            float v = tile[oct * 8 + o][jr] * iv;
            v = fminf(fmaxf(v, -127.0f), 127.0f);
            int q = (int)rintf(v);
            pk |= ((unsigned long long)(unsigned)(q & 0xFF)) << (8 * o);
        }
        *(unsigned long long*)(dst + (size_t)(j0 + jr) * C_DIM + c0 + oct * 8) = pk;
    }
}

// --- 3. 128x128-tile i8 GEMM, 4 waves, 2 blocks/CU, 1 phase per K-tile ---
// XCD swizzle: xcd = bid&7 owns split xcd>>1 -> that split's B panel (3MB)
// stays L2-resident on its XCD; A tiles (98KB/block) are L3-resident.
// Phase: {16 ds_read (both k-halves) | stage A,B(t+2) into live buf | 32 MFMA}
// then vmcnt(8) (waits t+1's 8 copies; t+2's 8 stay in flight) + barrier.
__global__ __launch_bounds__(256, 2) void nnfm_gemm_max(
    const u8* __restrict__ Xn, const u8* __restrict__ Sn,
    float* __restrict__ wmax) {
    __shared__ __align__(16) u8 smA[2][128 * 128];
    __shared__ __align__(16) u8 smB[2][128 * 128];

    const int bid = blockIdx.x;
    const int xcd = bid & 7;
    const int split = xcd >> 1;
    const int iblk = ((xcd & 1) << 6) + (bid >> 3);
    const int i0 = iblk * 128;
    const int jbase = split * (P_DIM / JSPLIT);

    const int tid = threadIdx.x;
    const int lane = tid & 63;
    const int wid = tid >> 6;
    const int wrow = (wid >> 1) * 64;
    const int wcol = (wid & 1) * 64;
    const int lm = lane & 15;

    const int srow = wid * 8 + (lane >> 3);                // + c*32 during staging
    const int scol = ((lane & 7) ^ (lane >> 3)) * 16;      // bytes, swizzled source col
    const int kidx0 = (((lane >> 4) + 0) ^ (lane & 7)) * 16;
    const int kidx1 = (((lane >> 4) + 4) ^ (lane & 7)) * 16;

#define STAGE_A(kk_t, buf_t) { \
    _Pragma("unroll") \
    for (int c = 0; c < 4; ++c) \
      async_copy16(Xn + (size_t)(i0 + c * 32 + srow) * C_DIM + (kk_t) * 128 + scol, \
                   &smA[buf_t][(c * 32 + wid * 8) * 128]); }

#define STAGE_B(jt_t, kk_t, buf_t) { \
    _Pragma("unroll") \
    for (int c = 0; c < 4; ++c) \
      async_copy16(Sn + (size_t)(jbase + (jt_t) * 128 + c * 32 + srow) * C_DIM + (kk_t) * 128 + scol, \
                   &smB[buf_t][(c * 32 + wid * 8) * 128]); }

#define RD_AB(BUF) { \
    _Pragma("unroll") \
    for (int m = 0; m < 4; ++m) { \
      aF[m][0] = *(const i32x4*)&smA[BUF][(wrow + m * 16 + lm) * 128 + kidx0]; \
      aF[m][1] = *(const i32x4*)&smA[BUF][(wrow + m * 16 + lm) * 128 + kidx1]; \
    } \
    _Pragma("unroll") \
    for (int n = 0; n < 4; ++n) { \
      bF[n][0] = *(const i32x4*)&smB[BUF][(wcol + n * 16 + lm) * 128 + kidx0]; \
      bF[n][1] = *(const i32x4*)&smB[BUF][(wcol + n * 16 + lm) * 128 + kidx1]; \
    } }

#define MFMA32(DOZERO) { \
    if (DOZERO) { \
      _Pragma("unroll") \
      for (int m = 0; m < 4; ++m) \
        _Pragma("unroll") \
        for (int n = 0; n < 4; ++n) \
          acc[m][n] = i32x4{0, 0, 0, 0}; \
    } \
    __builtin_amdgcn_s_setprio(1); \
    _Pragma("unroll") \
    for (int ks = 0; ks < 2; ++ks) \
      _Pragma("unroll") \
      for (int m = 0; m < 4; ++m) \
        _Pragma("unroll") \
        for (int n = 0; n < 4; ++n) \
          acc[m][n] = __builtin_amdgcn_mfma_i32_16x16x64_i8(aF[m][ks], bF[n][ks], acc[m][n], 0, 0, 0); \
    __builtin_amdgcn_s_setprio(0); }

    i32x4 acc[4][4];
    int rmax[4][4];
    i32x4 aF[4][2], bF[4][2];
    #pragma unroll
    for (int m = 0; m < 4; ++m)
        #pragma unroll
        for (int r = 0; r < 4; ++r) rmax[m][r] = (int)0x80000000;

    // prologue: tile0 (8 copies) + tile1 (8); need tile0 landed -> vmcnt(8)
    STAGE_A(0, 0); STAGE_B(0, 0, 0);
    STAGE_A(1, 1); STAGE_B(0, 1, 1);
    asm volatile("s_waitcnt vmcnt(8)" ::: "memory");
    BARRIER();

    for (int jt = 0; jt < NJT; ++jt) {
        for (int kk = 0; kk < KT; ++kk) {
            const int buf = kk & 1;
            int kk2 = kk + 2, jt2 = jt;
            if (kk2 >= KT) { kk2 -= KT; jt2 = (jt + 1) & (NJT - 1); }
            const bool z = (kk == 0), rx = (kk == KT - 1);

            RD_AB(buf)
            STAGE_A(kk2, buf); STAGE_B(jt2, kk2, buf);   // into live buf after reads
            MFMA32(z)
            if (rx) {
                #pragma unroll
                for (int m = 0; m < 4; ++m)
                    #pragma unroll
                    for (int r = 0; r < 4; ++r) {
                        int mx = acc[m][0][r];
                        #pragma unroll
                        for (int n = 1; n < 4; ++n)
                            if (acc[m][n][r] > mx) mx = acc[m][n][r];
                        if (mx > rmax[m][r]) rmax[m][r] = mx;
                    }
            }
            asm volatile("s_waitcnt vmcnt(8)" ::: "memory");
            BARRIER();
        }
    }

    // epilogue: drain all DMA before reusing LDS
    asm volatile("s_waitcnt vmcnt(0) lgkmcnt(0)" ::: "memory");
    BARRIER();

    const float isc = 1.0f / (QSCALE * QSCALE);
    float* red = (float*)&smA[0][0];   // [2 col-waves][128 rows]
    #pragma unroll
    for (int m = 0; m < 4; ++m)
        #pragma unroll
        for (int r = 0; r < 4; ++r) {
            int v = rmax[m][r];
            int o;
            o = __shfl_xor(v, 1); if (o > v) v = o;
            o = __shfl_xor(v, 2); if (o > v) v = o;
            o = __shfl_xor(v, 4); if (o > v) v = o;
            o = __shfl_xor(v, 8); if (o > v) v = o;
            if (lm == 0) {
                const int row_l = wrow + m * 16 + (lane >> 4) * 4 + r;
                red[(wid & 1) * 128 + row_l] = (float)v * isc;
            }
        }
    BARRIER();
    if (tid < 128) {
        wmax[(size_t)split * P_DIM + i0 + tid] = fmaxf(red[tid], red[128 + tid]);
    }
}

// --- 4. loss = mean(1 - max over 4 partials) ---
__global__ void final_reduce(const float* __restrict__ wmax, float* __restrict__ out) {
    __shared__ float red[256];
    int t = threadIdx.x;
    float sum = 0.f;
    for (int i = t; i < P_DIM; i += 256) {
        float m = wmax[i];
        #pragma unroll
        for (int sp = 1; sp < 4; ++sp) m = fmaxf(m, wmax[(size_t)sp * P_DIM + i]);
        sum += 1.0f - m;
    }
    red[t] = sum;
    __syncthreads();
    for (int st = 128; st > 0; st >>= 1) {
        if (t < st) red[t] += red[t + st];
        __syncthreads();
    }
    if (t == 0) out[0] = red[0] * (1.0f / (float)P_DIM);
}

extern "C" void kernel_launch(void* const* d_in, const int* in_sizes, int n_in,
                              void* d_out, int out_size, void* d_ws, size_t ws_size,
                              hipStream_t stream) {
    const float* x = (const float*)d_in[0];
    const float* s = (const float*)d_in[1];
    float* out = (float*)d_out;
    char* ws = (char*)d_ws;

    u8* Xn = (u8*)(ws + OFF_XN);
    u8* Sn = (u8*)(ws + OFF_SN);
    float* invx = (float*)(ws + OFF_INVX);
    float* invs = (float*)(ws + OFF_INVS);
    float* wmax = (float*)(ws + OFF_MAX);

    norm_kernel<<<dim3(64, 2), 256, 0, stream>>>(x, s, invx, invs);
    tnorm_kernel<<<dim3(256, 12, 2), 256, 0, stream>>>(x, s, invx, invs, Xn, Sn);
    nnfm_gemm_max<<<dim3((P_DIM / 128) * JSPLIT), 256, 0, stream>>>(Xn, Sn, wmax);
    final_reduce<<<1, 256, 0, stream>>>(wmax, out);
}

// Round 10
// 239.219 us; speedup vs baseline: 2.2353x; 1.2372x over previous
//
#include <hip/hip_runtime.h>
#include <math.h>

// NNFM loss on MI355X.
// loss = mean_i (1 - max_j (xhat_i . shat_j)),  xhat/shat = column-normalized feats.
// R2: XOR-swizzle -> 0 conflicts. R3: 256^2 8-wave phases. R4: reg-dbuf spill (rev).
// R5: fp8 BK=128 320us. R6: MX-scale spill (rev). R7: i8 16x16x64 327us (lockstep wall).
// R8: 128^2 4-wave 64KB LDS, 2 blocks/CU overlap -> 239us GEMM.
// R9: merged phase + XCD-split swizzle -> neutral; counters show beyond-L2 BW ceiling:
//     FETCH 740MB at ~3.2TB/s == kernel duration. A panels thrash L2 (6.3MB/XCD, 32x restage).
// R10: L2-residency mapping only: XCD x owns iblks [16x,16x+16) x all 4 splits ->
//      A working set 1.5MB/XCD (resident), B tiles shared 16-ways while streaming.

#define C_DIM 768
#define P_DIM 16384
#define KT 6            // K-tiles (BK=128) : 768/128
#define NJT 32          // j-tiles per block: 4096/128
#define JSPLIT 4
#define EPSF 1e-8f
#define QSCALE 256.0f

typedef unsigned char u8;
typedef int i32x4 __attribute__((ext_vector_type(4)));

// workspace layout (bytes)
#define OFF_XN   0
#define OFF_SN   25165824UL
#define OFF_INVX 50331648UL
#define OFF_INVS 50397184UL
#define OFF_MAX  50462720UL                 // 4 * 16384 * 4

__device__ __forceinline__ void async_copy16(const void* gsrc, void* ldst) {
    __builtin_amdgcn_global_load_lds(
        (const __attribute__((address_space(1))) void*)gsrc,
        (__attribute__((address_space(3))) void*)ldst,
        16, 0, 0);
}

#define CFENCE() asm volatile("" ::: "memory")
#define BARRIER() { CFENCE(); __builtin_amdgcn_s_barrier(); CFENCE(); }

// --- 1. column L2 norms: inv = QSCALE/(||col|| + eps); one thread per column ---
__global__ void norm_kernel(const float* __restrict__ x, const float* __restrict__ s,
                            float* __restrict__ invx, float* __restrict__ invs) {
    const float* src = blockIdx.y == 0 ? x : s;
    float* dst = (blockIdx.y == 0) ? invx : invs;
    int j = blockIdx.x * 256 + threadIdx.x;        // 0..16383
    float sum = 0.f;
    for (int c = 0; c < C_DIM; ++c) {
        float v = src[(size_t)c * P_DIM + j];
        sum += v * v;
    }
    dst[j] = QSCALE / (sqrtf(sum) + EPSF);
}

// --- 2. transpose [c][p] -> [p][c], normalize*256, round to int8 ---
__global__ void tnorm_kernel(const float* __restrict__ x, const float* __restrict__ s,
                             const float* __restrict__ invx, const float* __restrict__ invs,
                             u8* __restrict__ Xn, u8* __restrict__ Sn) {
    __shared__ float tile[64][65];
    const float* src = blockIdx.z ? s : x;
    const float* inv = blockIdx.z ? invs : invx;
    u8* dst = blockIdx.z ? Sn : Xn;
    int c0 = blockIdx.y * 64;
    int j0 = blockIdx.x * 64;
    int t = threadIdx.x;
    #pragma unroll
    for (int it = 0; it < 16; ++it) {
        int idx = it * 256 + t;
        int cr = idx >> 6, jc = idx & 63;
        tile[cr][jc] = src[(c0 + cr) * P_DIM + j0 + jc];
    }
    __syncthreads();
    #pragma unroll
    for (int it = 0; it < 2; ++it) {
        int item = it * 256 + t;
        int jr = item >> 3;
        int oct = item & 7;
        float iv = inv[j0 + jr];
        unsigned long long pk = 0;
        #pragma unroll
        for (int o = 0; o < 8; ++o) {
            float v = tile[oct * 8 + o][jr] * iv;
            v = fminf(fmaxf(v, -127.0f), 127.0f);
            int q = (int)rintf(v);
            pk |= ((unsigned long long)(unsigned)(q & 0xFF)) << (8 * o);
        }
        *(unsigned long long*)(dst + (size_t)(j0 + jr) * C_DIM + c0 + oct * 8) = pk;
    }
}

// --- 3. 128x128-tile i8 GEMM, 4 waves, 2 blocks/CU, 1 phase per K-tile ---
// L2-residency mapping: xcd = bid&7 owns iblks [xcd*16, xcd*16+16) x all 4 splits.
// A working set/XCD = 16 x 98KB = 1.5MB (L2-resident across its 32x restage);
// B tiles stream but are shared by the 16 same-split blocks sweeping in lockstep.
__global__ __launch_bounds__(256, 2) void nnfm_gemm_max(
    const u8* __restrict__ Xn, const u8* __restrict__ Sn,
    float* __restrict__ wmax) {
    __shared__ __align__(16) u8 smA[2][128 * 128];
    __shared__ __align__(16) u8 smB[2][128 * 128];

    const int bid = blockIdx.x;
    const int xcd = bid & 7;
    const int idx = bid >> 3;               // 0..63
    const int iblk = xcd * 16 + (idx & 15);
    const int split = idx >> 4;             // 0..3
    const int i0 = iblk * 128;
    const int jbase = split * (P_DIM / JSPLIT);

    const int tid = threadIdx.x;
    const int lane = tid & 63;
    const int wid = tid >> 6;
    const int wrow = (wid >> 1) * 64;
    const int wcol = (wid & 1) * 64;
    const int lm = lane & 15;

    const int srow = wid * 8 + (lane >> 3);                // + c*32 during staging
    const int scol = ((lane & 7) ^ (lane >> 3)) * 16;      // bytes, swizzled source col
    const int kidx0 = (((lane >> 4) + 0) ^ (lane & 7)) * 16;
    const int kidx1 = (((lane >> 4) + 4) ^ (lane & 7)) * 16;

#define STAGE_A(kk_t, buf_t) { \
    _Pragma("unroll") \
    for (int c = 0; c < 4; ++c) \
      async_copy16(Xn + (size_t)(i0 + c * 32 + srow) * C_DIM + (kk_t) * 128 + scol, \
                   &smA[buf_t][(c * 32 + wid * 8) * 128]); }

#define STAGE_B(jt_t, kk_t, buf_t) { \
    _Pragma("unroll") \
    for (int c = 0; c < 4; ++c) \
      async_copy16(Sn + (size_t)(jbase + (jt_t) * 128 + c * 32 + srow) * C_DIM + (kk_t) * 128 + scol, \
                   &smB[buf_t][(c * 32 + wid * 8) * 128]); }

#define RD_AB(BUF) { \
    _Pragma("unroll") \
    for (int m = 0; m < 4; ++m) { \
      aF[m][0] = *(const i32x4*)&smA[BUF][(wrow + m * 16 + lm) * 128 + kidx0]; \
      aF[m][1] = *(const i32x4*)&smA[BUF][(wrow + m * 16 + lm) * 128 + kidx1]; \
    } \
    _Pragma("unroll") \
    for (int n = 0; n < 4; ++n) { \
      bF[n][0] = *(const i32x4*)&smB[BUF][(wcol + n * 16 + lm) * 128 + kidx0]; \
      bF[n][1] = *(const i32x4*)&smB[BUF][(wcol + n * 16 + lm) * 128 + kidx1]; \
    } }

#define MFMA32(DOZERO) { \
    if (DOZERO) { \
      _Pragma("unroll") \
      for (int m = 0; m < 4; ++m) \
        _Pragma("unroll") \
        for (int n = 0; n < 4; ++n) \
          acc[m][n] = i32x4{0, 0, 0, 0}; \
    } \
    __builtin_amdgcn_s_setprio(1); \
    _Pragma("unroll") \
    for (int ks = 0; ks < 2; ++ks) \
      _Pragma("unroll") \
      for (int m = 0; m < 4; ++m) \
        _Pragma("unroll") \
        for (int n = 0; n < 4; ++n) \
          acc[m][n] = __builtin_amdgcn_mfma_i32_16x16x64_i8(aF[m][ks], bF[n][ks], acc[m][n], 0, 0, 0); \
    __builtin_amdgcn_s_setprio(0); }

    i32x4 acc[4][4];
    int rmax[4][4];
    i32x4 aF[4][2], bF[4][2];
    #pragma unroll
    for (int m = 0; m < 4; ++m)
        #pragma unroll
        for (int r = 0; r < 4; ++r) rmax[m][r] = (int)0x80000000;

    // prologue: tile0 (8 copies) + tile1 (8); need tile0 landed -> vmcnt(8)
    STAGE_A(0, 0); STAGE_B(0, 0, 0);
    STAGE_A(1, 1); STAGE_B(0, 1, 1);
    asm volatile("s_waitcnt vmcnt(8)" ::: "memory");
    BARRIER();

    for (int jt = 0; jt < NJT; ++jt) {
        for (int kk = 0; kk < KT; ++kk) {
            const int buf = kk & 1;
            int kk2 = kk + 2, jt2 = jt;
            if (kk2 >= KT) { kk2 -= KT; jt2 = (jt + 1) & (NJT - 1); }
            const bool z = (kk == 0), rx = (kk == KT - 1);

            RD_AB(buf)
            STAGE_A(kk2, buf); STAGE_B(jt2, kk2, buf);   // into live buf after reads
            MFMA32(z)
            if (rx) {
                #pragma unroll
                for (int m = 0; m < 4; ++m)
                    #pragma unroll
                    for (int r = 0; r < 4; ++r) {
                        int mx = acc[m][0][r];
                        #pragma unroll
                        for (int n = 1; n < 4; ++n)
                            if (acc[m][n][r] > mx) mx = acc[m][n][r];
                        if (mx > rmax[m][r]) rmax[m][r] = mx;
                    }
            }
            asm volatile("s_waitcnt vmcnt(8)" ::: "memory");
            BARRIER();
        }
    }

    // epilogue: drain all DMA before reusing LDS
    asm volatile("s_waitcnt vmcnt(0) lgkmcnt(0)" ::: "memory");
    BARRIER();

    const float isc = 1.0f / (QSCALE * QSCALE);
    float* red = (float*)&smA[0][0];   // [2 col-waves][128 rows]
    #pragma unroll
    for (int m = 0; m < 4; ++m)
        #pragma unroll
        for (int r = 0; r < 4; ++r) {
            int v = rmax[m][r];
            int o;
            o = __shfl_xor(v, 1); if (o > v) v = o;
            o = __shfl_xor(v, 2); if (o > v) v = o;
            o = __shfl_xor(v, 4); if (o > v) v = o;
            o = __shfl_xor(v, 8); if (o > v) v = o;
            if (lm == 0) {
                const int row_l = wrow + m * 16 + (lane >> 4) * 4 + r;
                red[(wid & 1) * 128 + row_l] = (float)v * isc;
            }
        }
    BARRIER();
    if (tid < 128) {
        wmax[(size_t)split * P_DIM + i0 + tid] = fmaxf(red[tid], red[128 + tid]);
    }
}

// --- 4. loss = mean(1 - max over 4 partials) ---
__global__ void final_reduce(const float* __restrict__ wmax, float* __restrict__ out) {
    __shared__ float red[256];
    int t = threadIdx.x;
    float sum = 0.f;
    for (int i = t; i < P_DIM; i += 256) {
        float m = wmax[i];
        #pragma unroll
        for (int sp = 1; sp < 4; ++sp) m = fmaxf(m, wmax[(size_t)sp * P_DIM + i]);
        sum += 1.0f - m;
    }
    red[t] = sum;
    __syncthreads();
    for (int st = 128; st > 0; st >>= 1) {
        if (t < st) red[t] += red[t + st];
        __syncthreads();
    }
    if (t == 0) out[0] = red[0] * (1.0f / (float)P_DIM);
}

extern "C" void kernel_launch(void* const* d_in, const int* in_sizes, int n_in,
                              void* d_out, int out_size, void* d_ws, size_t ws_size,
                              hipStream_t stream) {
    const float* x = (const float*)d_in[0];
    const float* s = (const float*)d_in[1];
    float* out = (float*)d_out;
    char* ws = (char*)d_ws;

    u8* Xn = (u8*)(ws + OFF_XN);
    u8* Sn = (u8*)(ws + OFF_SN);
    float* invx = (float*)(ws + OFF_INVX);
    float* invs = (float*)(ws + OFF_INVS);
    float* wmax = (float*)(ws + OFF_MAX);

    norm_kernel<<<dim3(64, 2), 256, 0, stream>>>(x, s, invx, invs);
    tnorm_kernel<<<dim3(256, 12, 2), 256, 0, stream>>>(x, s, invx, invs, Xn, Sn);
    nnfm_gemm_max<<<dim3((P_DIM / 128) * JSPLIT), 256, 0, stream>>>(Xn, Sn, wmax);
    final_reduce<<<1, 256, 0, stream>>>(wmax, out);
}